// Round 4
// baseline (35.169 us; speedup 1.0000x reference)
//
#include <hip/hip_runtime.h>

constexpr int B   = 1024;
constexpr int N   = 4096;
constexpr int BLK = 512;                  // stage-1 block = 8 waves
constexpr int VPT = 2;                    // independent strided n's per thread
constexpr int BLOCKS_PER_BATCH = N / (BLK * VPT);   // = 4
constexpr int WAVES_PER_BATCH  = BLOCKS_PER_BATCH * (BLK / 64);  // = 32
constexpr float C01 = 0.4082482904638630f;  // sqrt(0.5)/sqrt(3)
constexpr float C11 = 0.2886751345948129f;  // sqrt(0.5)/sqrt(6)

typedef float f32x4 __attribute__((ext_vector_type(4)));

// Stage 1: grid = B*4 blocks x 512 threads; thread handles n and n+512
// (both lane-dense per instruction). Pure shuffle reduce, per-wave partial.
__global__ __launch_bounds__(BLK) void tp_reduce_kernel(
    const float* __restrict__ feats,      // (B, N, 8)
    const float* __restrict__ edge_attr,  // (B, N, 3)
    const float* __restrict__ w_path0,    // (5,)
    const float* __restrict__ w_path1,    // (1,)
    float* __restrict__ part)             // (B*32, 3) per-wave partials
{
    const int blk = blockIdx.x;
    const int b   = blk >> 2;
    const int q   = blk & 3;
    const int t   = threadIdx.x;
    const int n0  = (q << 10) + t;        // q*1024 + t
    const long base = (long)b * N;

    // issue both load streams up front (independent)
    const f32x4* fp0 = reinterpret_cast<const f32x4*>(feats + (base + n0) * 8);
    const f32x4* fp1 = reinterpret_cast<const f32x4*>(feats + (base + n0 + 512) * 8);
    f32x4 fa0 = __builtin_nontemporal_load(fp0);
    f32x4 fa1 = __builtin_nontemporal_load(fp0 + 1);
    f32x4 fb0 = __builtin_nontemporal_load(fp1);
    f32x4 fb1 = __builtin_nontemporal_load(fp1 + 1);

    const float* ea = edge_attr + (base + n0) * 3;
    const float* eb = edge_attr + (base + n0 + 512) * 3;
    float ea0 = __builtin_nontemporal_load(ea);
    float ea1 = __builtin_nontemporal_load(ea + 1);
    float ea2 = __builtin_nontemporal_load(ea + 2);
    float eb0 = __builtin_nontemporal_load(eb);
    float eb1 = __builtin_nontemporal_load(eb + 1);
    float eb2 = __builtin_nontemporal_load(eb + 2);

    const float w0 = w_path0[0], w1 = w_path0[1], w2 = w_path0[2],
                w3 = w_path0[3], w4 = w_path0[4];
    const float c11w = C11 * w_path1[0];

    float sA = fa0.x * w0 + fa0.y * w1 + fa0.z * w2 + fa0.w * w3 + fa1.x * w4;
    float sB = fb0.x * w0 + fb0.y * w1 + fb0.z * w2 + fb0.w * w3 + fb1.x * w4;
    float cA = C01 * sA, cB = C01 * sB;

    float t0 = cA * ea0 + c11w * (fa1.z * ea2 - fa1.w * ea1)
             + cB * eb0 + c11w * (fb1.z * eb2 - fb1.w * eb1);
    float t1 = cA * ea1 + c11w * (fa1.w * ea0 - fa1.y * ea2)
             + cB * eb1 + c11w * (fb1.w * eb0 - fb1.y * eb2);
    float t2 = cA * ea2 + c11w * (fa1.y * ea1 - fa1.z * ea0)
             + cB * eb2 + c11w * (fb1.y * eb1 - fb1.z * eb0);

    #pragma unroll
    for (int off = 32; off > 0; off >>= 1) {
        t0 += __shfl_down(t0, off);
        t1 += __shfl_down(t1, off);
        t2 += __shfl_down(t2, off);
    }

    if ((t & 63) == 0) {
        const int w = (q << 3) + (t >> 6);  // wave index within batch, 0..31
        float* p = part + ((long)b * WAVES_PER_BATCH + w) * 3;
        p[0] = t0;
        p[1] = t1;
        p[2] = t2;
    }
}

// Stage 2: one wave per batch. Lanes 0..31 load partials; MLP 3->128(relu)->3.
__global__ __launch_bounds__(64) void mlp_kernel(
    const float* __restrict__ part,  // (B*32, 3)
    const float* __restrict__ W1,    // (3, 128)
    const float* __restrict__ b1,    // (128,)
    const float* __restrict__ W2,    // (128, 3)
    const float* __restrict__ b2,    // (3,)
    float* __restrict__ out)         // (B, 3)
{
    const int b = blockIdx.x;
    const int l = threadIdx.x;  // 0..63

    float a0 = 0.0f, a1 = 0.0f, a2 = 0.0f;
    if (l < WAVES_PER_BATCH) {
        const float* p = part + ((long)b * WAVES_PER_BATCH + l) * 3;
        a0 = p[0]; a1 = p[1]; a2 = p[2];
    }
    #pragma unroll
    for (int off = 32; off > 0; off >>= 1) {
        a0 += __shfl_down(a0, off);
        a1 += __shfl_down(a1, off);
        a2 += __shfl_down(a2, off);
    }
    const float g0 = __shfl(a0, 0) * (1.0f / (float)N);
    const float g1 = __shfl(a1, 0) * (1.0f / (float)N);
    const float g2 = __shfl(a2, 0) * (1.0f / (float)N);

    float p0 = 0.0f, p1 = 0.0f, p2 = 0.0f;
    #pragma unroll
    for (int half = 0; half < 2; ++half) {
        const int j = l + half * 64;
        float h = b1[j] + g0 * W1[j] + g1 * W1[128 + j] + g2 * W1[256 + j];
        h = fmaxf(h, 0.0f);
        p0 += h * W2[j * 3 + 0];
        p1 += h * W2[j * 3 + 1];
        p2 += h * W2[j * 3 + 2];
    }
    #pragma unroll
    for (int off = 32; off > 0; off >>= 1) {
        p0 += __shfl_down(p0, off);
        p1 += __shfl_down(p1, off);
        p2 += __shfl_down(p2, off);
    }
    if (l == 0) {
        float* o = out + (long)b * 3;
        o[0] = p0 + b2[0];
        o[1] = p1 + b2[1];
        o[2] = p2 + b2[2];
    }
}

extern "C" void kernel_launch(void* const* d_in, const int* in_sizes, int n_in,
                              void* d_out, int out_size, void* d_ws, size_t ws_size,
                              hipStream_t stream) {
    const float* feats     = (const float*)d_in[0];
    const float* edge_attr = (const float*)d_in[1];
    const float* w_path0   = (const float*)d_in[2];
    const float* w_path1   = (const float*)d_in[3];
    const float* W1        = (const float*)d_in[4];
    const float* b1        = (const float*)d_in[5];
    const float* W2        = (const float*)d_in[6];
    const float* b2        = (const float*)d_in[7];
    float* out = (float*)d_out;

    float* part = (float*)d_ws;  // B*32*3 floats = 384 KiB

    tp_reduce_kernel<<<B * BLOCKS_PER_BATCH, BLK, 0, stream>>>(
        feats, edge_attr, w_path0, w_path1, part);
    mlp_kernel<<<B, 64, 0, stream>>>(part, W1, b1, W2, b2, out);
}